// Round 9
// baseline (7205.579 us; speedup 1.0000x reference)
//
#include <hip/hip_runtime.h>
#include <hip/hip_bf16.h>

typedef __hip_bfloat16 bf16;
typedef __attribute__((ext_vector_type(8))) short short8;
typedef __attribute__((ext_vector_type(4))) float f32x4;

#define N_ 8
#define B_ 64
#define T_ 256
#define IN_ 64
#define H_ 512
#define G4_ 2048
#define M_ 512
#define O_ 7
#define HP 520   // padded LDS row stride (bf16)

__device__ __forceinline__ float sigf(float x) { return 1.0f / (1.0f + __expf(-x)); }
__device__ __forceinline__ float tanhfast(float x) { return 2.0f / (1.0f + __expf(-2.0f * x)) - 1.0f; }

// ---------------- convert fp32 -> bf16 ----------------
__global__ void cvt_kernel(const float* __restrict__ src, bf16* __restrict__ dst, int n4) {
  for (int i = blockIdx.x * blockDim.x + threadIdx.x; i < n4; i += gridDim.x * blockDim.x) {
    float4 v = ((const float4*)src)[i];
    bf16 t0 = __float2bfloat16(v.x), t1 = __float2bfloat16(v.y);
    bf16 t2 = __float2bfloat16(v.z), t3 = __float2bfloat16(v.w);
    ushort4 o;
    o.x = *(unsigned short*)&t0; o.y = *(unsigned short*)&t1;
    o.z = *(unsigned short*)&t2; o.w = *(unsigned short*)&t3;
    ((ushort4*)dst)[i] = o;
  }
}

// ---------------- K1: z = leaky(x@Win^T + bin)*10 ----------------
__global__ void input_kernel(const float* __restrict__ x, const float* __restrict__ Win,
                             const float* __restrict__ bin, bf16* __restrict__ z) {
  int bid = blockIdx.x;
  int t = bid >> 6;
  int b = bid & 63;
  __shared__ float xr[IN_];
  int tid = threadIdx.x;
  if (tid < IN_) xr[tid] = x[((size_t)b * T_ + t) * IN_ + tid];
  __syncthreads();
  for (int h = tid; h < H_; h += 256) {
    const float* w = Win + (size_t)h * IN_;
    float s = bin[h];
#pragma unroll 16
    for (int i = 0; i < IN_; ++i) s += xr[i] * w[i];
    s = (s > 0.f ? s : 0.2f * s) * 10.f;
    z[((size_t)t * B_ + b) * H_ + h] = __float2bfloat16(s);
  }
}

// ---------------- K2: persistent LSTM scan, 2-gate waves + pipelined staging ----------------
// 256 blocks x 512 thr. Block (n, ub): 16 hidden/M units of model n.
// Wave roles (p = w&1 -> gates {2p, 2p+1}):
//   w0,w1: L0-hh (A=hs=h0(s-1))        -> S0 slots 4+g
//   w2,w3: L1-ih (A=hs=h0(s-1), bias)  -> S1 slots g
//   w4,w5: L0-ih (A=z(s) global L2, bias)-> S0 slots g      [runs in P1]
//   w6,w7: L1-hh (A=hs=h1(s-2))        -> S1 slots 4+g     [runs in P4]
// Each wave holds TWO B-frags (128 regs) -> one A ds_read feeds 2 MFMAs:
// hs(h0) is read by 4 waves instead of 8 (halved LDS amplification vs R8).
// Staging pipelined: w0-3 stage h0 under w4/w5's z-matmul (P1); w4-7 issue
// h1 loads in P2 (latency hidden under MFMA), write in P3 under EW-L0.
// Sync protocol: EXACTLY R8's proven fence-free one (sc1 write-through stores,
// sc1 MALL-direct reads, relaxed flag store after vmcnt-draining barrier,
// relaxed poll, periodic fence as liveness guard only).
__global__ void __launch_bounds__(512, 2) scan_kernel(
    const bf16* __restrict__ z,
    const bf16* __restrict__ Wih0, const bf16* __restrict__ Whh0,
    const float* __restrict__ bih0, const float* __restrict__ bhh0,
    const bf16* __restrict__ Wih1, const bf16* __restrict__ Whh1,
    const float* __restrict__ bih1, const float* __restrict__ bhh1,
    const bf16* __restrict__ Wh1, const float* __restrict__ bh1,
    const float* __restrict__ Wh2, const float* __restrict__ bh2,
    bf16* __restrict__ h0buf, bf16* __restrict__ h1buf,
    bf16* __restrict__ mstage, float* __restrict__ out,
    unsigned* __restrict__ flags)
{
  __shared__ float S0[8][B_][16];   // gate g: ih(z)-half -> slot g, hh-half -> 4+g
  __shared__ float S1[8][B_][16];
  __shared__ bf16 hs[B_][HP];       // staged slab: h0(s-1) in P1/P2, h1(s-2) in P3/P4
  __shared__ bf16 wh1s[16][HP];     // block's 16 Wh1 rows

  const int tid = threadIdx.x;
  const int lane = tid & 63;
  const int w = tid >> 6;      // 0..7
  const int p = w & 1;         // gate pair: gates 2p, 2p+1
  const int gA = 2 * p, gB = 2 * p + 1;
  const int q = lane >> 4;
  const int cl = lane & 15;
  const int bid = blockIdx.x;
  const int n = bid >> 5;
  const int blk = bid & 31;
  const int ub = blk << 4;

  const size_t NBH = (size_t)N_ * B_ * H_;
  const size_t NBM = (size_t)N_ * B_ * M_;

  // ---- per-wave weight matrix + bias + S-slot selection ----
  const bf16* Wsel;
  const float *bselA = nullptr, *bselB = nullptr;   // bias source (two arrays summed)
  const float *bsel2A = nullptr, *bsel2B = nullptr;
  float (*SA)[16];
  float (*SB)[16];
  if (w < 2)      { Wsel = Whh0; SA = S0[4 + gA]; SB = S0[4 + gB]; }
  else if (w < 4) { Wsel = Wih1; SA = S1[gA];     SB = S1[gB];
                    bselA = bih1; bselB = bhh1; }
  else if (w < 6) { Wsel = Wih0; SA = S0[gA];     SB = S0[gB];
                    bselA = bih0; bselB = bhh0; }
  else            { Wsel = Whh1; SA = S1[4 + gA]; SB = S1[4 + gB]; }
  (void)bsel2A; (void)bsel2B;

  const size_t wrowA = (size_t)n * G4_ * H_ + (size_t)(gA * H_ + ub + cl) * H_ + q * 8;
  const size_t wrowB = (size_t)n * G4_ * H_ + (size_t)(gB * H_ + ub + cl) * H_ + q * 8;
  short8 wlA[16], wlB[16];
#pragma unroll
  for (int kk = 0; kk < 16; ++kk) {
    wlA[kk] = *(const short8*)(Wsel + wrowA + kk * 32);
    wlB[kk] = *(const short8*)(Wsel + wrowB + kk * 32);
  }
  float bA = 0.f, bB = 0.f;
  if (bselA) {
    const int iA = n * G4_ + gA * H_ + ub + cl;
    const int iB = n * G4_ + gB * H_ + ub + cl;
    bA = bselA[iA] + bselB[iA];
    bB = bselA[iB] + bselB[iB];
  }
  const float bh1v = bh1[n * M_ + ub + cl];   // H1 bias (waves 0..3)

  // ---- one-time Wh1 -> LDS ----
  {
    const bf16* wsrc = Wh1 + (size_t)n * M_ * H_ + (size_t)ub * H_;
    for (int i = tid; i < 16 * 64; i += 512) {
      int row = i >> 6, c8 = (i & 63) * 8;
      *(short8*)&wh1s[row][c8] = *(const short8*)(wsrc + (size_t)row * H_ + c8);
    }
  }
  float c0r0 = 0.f, c0r1 = 0.f, c1r0 = 0.f, c1r1 = 0.f;  // c-state in regs
  __syncthreads();

  unsigned* myflag   = flags + (size_t)n * 64 + blk;
  unsigned* pollbase = flags + (size_t)n * 64;

  for (int s = 0; s < T_ + 3; ++s) {
    const bool doL0 = (s < T_);
    const bool doL1 = (s >= 1 && s <= T_);
    const bool doH1 = (s >= 2 && s <= T_ + 1);
    const bool doH2 = (s >= 3);
    const bool st0  = (s <= T_);
    const bool st1  = (s >= 1 && s <= T_ + 1);

    // ================= P1: stage hs=h0(s-1) (w0-3) || z-MFMA (w4,w5) =================
    if (w < 4) {
      if (st0) {
        const bf16* src = h0buf + (size_t)((s & 1) ^ 1) * NBH + (size_t)n * B_ * H_;
#pragma unroll
        for (int rd = 0; rd < 2; ++rd) {
          unsigned long long va[16];
#pragma unroll
          for (int it = 0; it < 8; ++it) {
            int i = tid + (rd * 8 + it) * 256;
            int row = i >> 6, c16 = i & 63;
            const unsigned long long* gp =
                (const unsigned long long*)(src + (size_t)row * H_ + c16 * 8);
            va[it * 2]     = __hip_atomic_load(gp,     __ATOMIC_RELAXED, __HIP_MEMORY_SCOPE_AGENT);
            va[it * 2 + 1] = __hip_atomic_load(gp + 1, __ATOMIC_RELAXED, __HIP_MEMORY_SCOPE_AGENT);
          }
#pragma unroll
          for (int it = 0; it < 8; ++it) {
            int i = tid + (rd * 8 + it) * 256;
            int row = i >> 6, c16 = i & 63;
            unsigned long long* lp = (unsigned long long*)&hs[row][c16 * 8];
            lp[0] = va[it * 2]; lp[1] = va[it * 2 + 1];
          }
        }
      }
    } else if (w < 6 && doL0) {
      // L0-ih from z (global, L2-hot) for gates gA,gB; write S0 slots gA,gB
      const bf16* A = z + (size_t)s * B_ * H_;
#pragma unroll
      for (int strip = 0; strip < 4; ++strip) {
        f32x4 aA = (f32x4){bA, bA, bA, bA};
        f32x4 aB = (f32x4){bB, bB, bB, bB};
        const bf16* Ap = A + (size_t)(strip * 16 + cl) * H_ + q * 8;
#pragma unroll
        for (int kk = 0; kk < 16; ++kk) {
          short8 a = *(const short8*)(Ap + kk * 32);
          aA = __builtin_amdgcn_mfma_f32_16x16x32_bf16(a, wlA[kk], aA, 0, 0, 0);
          aB = __builtin_amdgcn_mfma_f32_16x16x32_bf16(a, wlB[kk], aB, 0, 0, 0);
        }
#pragma unroll
        for (int r = 0; r < 4; ++r) {
          SA[strip * 16 + q * 4 + r][cl] = aA[r];
          SB[strip * 16 + q * 4 + r][cl] = aB[r];
        }
      }
    }
    __syncthreads();

    // ================= P2: hs-MFMA (w0-3) || issue h1 loads (w4-7) =================
    unsigned long long st[32];
    if (w < 4) {
      const bool act = (w < 2) ? doL0 : doL1;
      if (act) {
#pragma unroll
        for (int strip = 0; strip < 4; ++strip) {
          f32x4 aA = (f32x4){bA, bA, bA, bA};   // bA=0 for w0,w1
          f32x4 aB = (f32x4){bB, bB, bB, bB};
#pragma unroll
          for (int kk = 0; kk < 16; ++kk) {
            short8 a = *(const short8*)&hs[strip * 16 + cl][q * 8 + kk * 32];
            aA = __builtin_amdgcn_mfma_f32_16x16x32_bf16(a, wlA[kk], aA, 0, 0, 0);
            aB = __builtin_amdgcn_mfma_f32_16x16x32_bf16(a, wlB[kk], aB, 0, 0, 0);
          }
#pragma unroll
          for (int r = 0; r < 4; ++r) {
            SA[strip * 16 + q * 4 + r][cl] = aA[r];
            SB[strip * 16 + q * 4 + r][cl] = aB[r];
          }
        }
      }
    } else if (st1) {
      const bf16* src = h1buf + (size_t)(s & 1) * NBH + (size_t)n * B_ * H_;
      const int l = tid - 256;
#pragma unroll
      for (int it = 0; it < 16; ++it) {
        int i = l + it * 256;
        int row = i >> 6, c16 = i & 63;
        const unsigned long long* gp =
            (const unsigned long long*)(src + (size_t)row * H_ + c16 * 8);
        st[it * 2]     = __hip_atomic_load(gp,     __ATOMIC_RELAXED, __HIP_MEMORY_SCOPE_AGENT);
        st[it * 2 + 1] = __hip_atomic_load(gp + 1, __ATOMIC_RELAXED, __HIP_MEMORY_SCOPE_AGENT);
      }
    }
    __syncthreads();

    // ================= P3: write hs=h1(s-2) (w4-7) ; EW-L0 (all) =================
    if (w >= 4 && st1) {
      const int l = tid - 256;
#pragma unroll
      for (int it = 0; it < 16; ++it) {
        int i = l + it * 256;
        int row = i >> 6, c16 = i & 63;
        unsigned long long* lp = (unsigned long long*)&hs[row][c16 * 8];
        lp[0] = st[it * 2]; lp[1] = st[it * 2 + 1];
      }
    }
    if (doL0) {
      bf16* h0out = h0buf + (size_t)(s & 1) * NBH + (size_t)n * B_ * H_;
#pragma unroll
      for (int it = 0; it < 2; ++it) {
        int e = tid + it * 512;
        int row = e >> 4, ul = e & 15;
        float gi = S0[0][row][ul] + S0[4][row][ul];
        float gf = S0[1][row][ul] + S0[5][row][ul];
        float gg = S0[2][row][ul] + S0[6][row][ul];
        float go = S0[3][row][ul] + S0[7][row][ul];
        float c = it ? c0r1 : c0r0;
        float cn = sigf(gf) * c + sigf(gi) * tanhfast(gg);
        if (it) c0r1 = cn; else c0r0 = cn;
        float hv = sigf(go) * tanhfast(cn);
        bf16 hb16 = __float2bfloat16(hv);
        unsigned hb = *(unsigned short*)&hb16;
        unsigned nb = (unsigned)__shfl_xor((int)hb, 1, 64);
        if (!(ul & 1)) {
          unsigned word = hb | (nb << 16);
          __hip_atomic_store((unsigned*)(h0out + row * H_ + ub + ul), word,
                             __ATOMIC_RELAXED, __HIP_MEMORY_SCOPE_AGENT);
        }
      }
    }
    __syncthreads();

    // ================= P4: L1-hh (w6,w7) || H1 (w0-3) =================
    if (w >= 6 && doL1) {
#pragma unroll
      for (int strip = 0; strip < 4; ++strip) {
        f32x4 aA = (f32x4){0.f, 0.f, 0.f, 0.f};
        f32x4 aB = (f32x4){0.f, 0.f, 0.f, 0.f};
#pragma unroll
        for (int kk = 0; kk < 16; ++kk) {
          short8 a = *(const short8*)&hs[strip * 16 + cl][q * 8 + kk * 32];
          aA = __builtin_amdgcn_mfma_f32_16x16x32_bf16(a, wlA[kk], aA, 0, 0, 0);
          aB = __builtin_amdgcn_mfma_f32_16x16x32_bf16(a, wlB[kk], aB, 0, 0, 0);
        }
#pragma unroll
        for (int r = 0; r < 4; ++r) {
          SA[strip * 16 + q * 4 + r][cl] = aA[r];
          SB[strip * 16 + q * 4 + r][cl] = aB[r];
        }
      }
    }
    if (w < 4 && doH1) {
      const int tH1 = s - 2;
      f32x4 aH = (f32x4){bh1v, bh1v, bh1v, bh1v};
      for (int kk = 0; kk < H_; kk += 32) {
        short8 a = *(const short8*)&hs[w * 16 + cl][q * 8 + kk];
        short8 b = *(const short8*)&wh1s[cl][q * 8 + kk];
        aH = __builtin_amdgcn_mfma_f32_16x16x32_bf16(a, b, aH, 0, 0, 0);
      }
      bf16* msl = mstage + (size_t)(tH1 & 3) * NBM + (size_t)n * B_ * M_;
#pragma unroll
      for (int r = 0; r < 4; ++r) {
        float v = aH[r];
        v = v > 0.f ? v : 0.2f * v;
        bf16 vb = __float2bfloat16(v);
        unsigned hb = *(unsigned short*)&vb;
        unsigned nb = (unsigned)__shfl_xor((int)hb, 1, 64);
        if (!(cl & 1)) {
          unsigned word = hb | (nb << 16);
          __hip_atomic_store((unsigned*)(msl + (w * 16 + q * 4 + r) * M_ + ub + cl),
                             word, __ATOMIC_RELAXED, __HIP_MEMORY_SCOPE_AGENT);
        }
      }
    }
    __syncthreads();

    // ================= P5: EW-L1 =================
    if (doL1) {
      const int t = s - 1;
      bf16* h1out = h1buf + (size_t)(t & 1) * NBH + (size_t)n * B_ * H_;
#pragma unroll
      for (int it = 0; it < 2; ++it) {
        int e = tid + it * 512;
        int row = e >> 4, ul = e & 15;
        float gi = S1[0][row][ul] + S1[4][row][ul];
        float gf = S1[1][row][ul] + S1[5][row][ul];
        float gg = S1[2][row][ul] + S1[6][row][ul];
        float go = S1[3][row][ul] + S1[7][row][ul];
        float c = it ? c1r1 : c1r0;
        float cn = sigf(gf) * c + sigf(gi) * tanhfast(gg);
        if (it) c1r1 = cn; else c1r0 = cn;
        float hv = sigf(go) * tanhfast(cn);
        bf16 hb16 = __float2bfloat16(hv);
        unsigned hb = *(unsigned short*)&hb16;
        unsigned nb = (unsigned)__shfl_xor((int)hb, 1, 64);
        if (!(ul & 1)) {
          unsigned word = hb | (nb << 16);
          __hip_atomic_store((unsigned*)(h1out + row * H_ + ub + ul), word,
                             __ATOMIC_RELAXED, __HIP_MEMORY_SCOPE_AGENT);
        }
      }
    }
    __syncthreads();   // drains all sc1 data stores (P3 h0, P4 mstage, P5 h1)
    if (tid == 0)
      __hip_atomic_store(myflag, (unsigned)(s + 1), __ATOMIC_RELAXED,
                         __HIP_MEMORY_SCOPE_AGENT);

    // ================= barrier shadow: H2 (w4,w5) =================
    if (doH2 && (w == 4 || w == 5)) {
      const int tH2 = s - 3;
      const int b = blk * 2 + (w - 4);
      const int o = lane & 7;
      const int oc = o < 7 ? o : 0;
      const int mc = (lane >> 3) * 64;
      const bf16* ms = mstage + (size_t)(tH2 & 3) * NBM + ((size_t)n * B_ + b) * M_ + mc;
      const float* w2p = Wh2 + (size_t)n * O_ * M_ + (size_t)oc * M_ + mc;
      float pr = 0.f;
#pragma unroll
      for (int j = 0; j < 64; j += 8) {
        const unsigned long long* mp = (const unsigned long long*)(ms + j);
        unsigned long long u0 = __hip_atomic_load(mp,     __ATOMIC_RELAXED, __HIP_MEMORY_SCOPE_AGENT);
        unsigned long long u1 = __hip_atomic_load(mp + 1, __ATOMIC_RELAXED, __HIP_MEMORY_SCOPE_AGENT);
        float4 w0 = *(const float4*)(w2p + j);
        float4 w1 = *(const float4*)(w2p + j + 4);
        pr += __uint_as_float((unsigned)(u0 & 0xffffu) << 16) * w0.x
            + __uint_as_float((unsigned)((u0 >> 16) & 0xffffu) << 16) * w0.y
            + __uint_as_float((unsigned)((u0 >> 32) & 0xffffu) << 16) * w0.z
            + __uint_as_float((unsigned)((u0 >> 48) & 0xffffu) << 16) * w0.w
            + __uint_as_float((unsigned)(u1 & 0xffffu) << 16) * w1.x
            + __uint_as_float((unsigned)((u1 >> 16) & 0xffffu) << 16) * w1.y
            + __uint_as_float((unsigned)((u1 >> 32) & 0xffffu) << 16) * w1.z
            + __uint_as_float((unsigned)((u1 >> 48) & 0xffffu) << 16) * w1.w;
      }
      pr += __shfl_xor(pr, 8, 64);
      pr += __shfl_xor(pr, 16, 64);
      pr += __shfl_xor(pr, 32, 64);
      if (lane < 7) {
        pr += bh2[n * O_ + o];
        out[(((size_t)n * B_ + b) * T_ + tH2) * O_ + o] = pr;
      }
    }

    // ---- poll (w7): relaxed sc1 loads; periodic fence = liveness guard only ----
    if (w == 7) {
      const unsigned tgt = (unsigned)(s + 1);
      unsigned* fp = pollbase + (lane & 31);
      int spins = 0;
      while (__hip_atomic_load(fp, __ATOMIC_RELAXED, __HIP_MEMORY_SCOPE_AGENT) < tgt) {
        __builtin_amdgcn_s_sleep(2);
        if (++spins >= 256) {
          spins = 0;
          __builtin_amdgcn_fence(__ATOMIC_ACQUIRE, "agent");
        }
      }
    }
    __syncthreads();
  }
}

extern "C" void kernel_launch(void* const* d_in, const int* in_sizes, int n_in,
                              void* d_out, int out_size, void* d_ws, size_t ws_size,
                              hipStream_t stream) {
  (void)in_sizes; (void)n_in; (void)out_size; (void)ws_size;
  const float* x    = (const float*)d_in[0];
  const float* Win  = (const float*)d_in[1];
  const float* bin  = (const float*)d_in[2];
  const float* Wih0 = (const float*)d_in[3];
  const float* Whh0 = (const float*)d_in[4];
  const float* bih0 = (const float*)d_in[5];
  const float* bhh0 = (const float*)d_in[6];
  const float* Wih1 = (const float*)d_in[7];
  const float* Whh1 = (const float*)d_in[8];
  const float* bih1 = (const float*)d_in[9];
  const float* bhh1 = (const float*)d_in[10];
  const float* Wh1  = (const float*)d_in[11];
  const float* bh1  = (const float*)d_in[12];
  const float* Wh2  = (const float*)d_in[13];
  const float* bh2  = (const float*)d_in[14];

  const size_t WLSTM = (size_t)N_ * G4_ * H_;
  const size_t WH1   = (size_t)N_ * M_ * H_;
  const size_t NFLAG = (size_t)N_ * 64;

  char* ws = (char*)d_ws;
  size_t off = 0;
  bf16* zb     = (bf16*)(ws + off); off += (size_t)T_ * B_ * H_ * sizeof(bf16);
  bf16* Wih0b  = (bf16*)(ws + off); off += WLSTM * sizeof(bf16);
  bf16* Whh0b  = (bf16*)(ws + off); off += WLSTM * sizeof(bf16);
  bf16* Wih1b  = (bf16*)(ws + off); off += WLSTM * sizeof(bf16);
  bf16* Whh1b  = (bf16*)(ws + off); off += WLSTM * sizeof(bf16);
  bf16* Wh1b   = (bf16*)(ws + off); off += WH1 * sizeof(bf16);
  bf16* h0buf  = (bf16*)(ws + off); off += 2 * (size_t)N_ * B_ * H_ * sizeof(bf16);
  bf16* h1buf  = (bf16*)(ws + off); off += 2 * (size_t)N_ * B_ * H_ * sizeof(bf16);
  bf16* mstage = (bf16*)(ws + off); off += 4 * (size_t)N_ * B_ * M_ * sizeof(bf16);
  unsigned* flags = (unsigned*)(ws + off); off += NFLAG * sizeof(unsigned);

  // zero h/m state + flags (contiguous span)
  hipMemsetAsync(h0buf, 0, (char*)(flags + NFLAG) - (char*)h0buf, stream);

  cvt_kernel<<<dim3(2048), dim3(256), 0, stream>>>(Wih0, Wih0b, (int)(WLSTM / 4));
  cvt_kernel<<<dim3(2048), dim3(256), 0, stream>>>(Whh0, Whh0b, (int)(WLSTM / 4));
  cvt_kernel<<<dim3(2048), dim3(256), 0, stream>>>(Wih1, Wih1b, (int)(WLSTM / 4));
  cvt_kernel<<<dim3(2048), dim3(256), 0, stream>>>(Whh1, Whh1b, (int)(WLSTM / 4));
  cvt_kernel<<<dim3(1024), dim3(256), 0, stream>>>(Wh1, Wh1b, (int)(WH1 / 4));

  input_kernel<<<dim3(T_ * B_), dim3(256), 0, stream>>>(x, Win, bin, zb);

  scan_kernel<<<dim3(256), dim3(512), 0, stream>>>(
      zb, Wih0b, Whh0b, bih0, bhh0, Wih1b, Whh1b, bih1, bhh1,
      Wh1b, bh1, Wh2, bh2, h0buf, h1buf, mstage, (float*)d_out, flags);
}